// Round 11
// baseline (4469.003 us; speedup 1.0000x reference)
//
#include <hip/hip_runtime.h>
#include <hip/hip_bf16.h>

// LSTM_Net round 11: per-wave decoupled pipelines + aggregator sync + HOT heaters.
// r10 post-mortem: aggregator tree -0.6us -> RMW fan-in not the floor either.
// Remaining un-attacked combination:
//  (a) clock sag persists: r9/r10 heaters were dependent-FMA chains (~25%
//      issue) -> weak DPM signal (VALUBusy 6.5%). Rebuilt: 8 independent
//      accumulators, ~100% issue density on heater CUs.
//  (b) chain depth: consumer wave w only reads rows produced by producer
//      wave w (m-tile w of every col-WG) -> the 4 m-tile pipelines per layer
//      are independent. Removed BOTH __syncthreads from the loop: per-wave
//      publish (256B sc1 store + vmcnt drain + per-wave flag), per-wave
//      epoch polling. 8 aggregator waves (one per layer x m-tile) scan 96
//      flags each, broadcast to 8 replica lines. (Clean rerun of r8's idea,
//      which was confounded by heaters polling live lines.)
// ctrs layout (ints): fl0[wrow][cb] @ wrow*128+cb; fl1 @ 512+...;
// ep0[wrow][rep] @ 1024+wrow*128+rep*16; ep1 @ 1536+...; done @ 2048.

#define B_  64
#define T_  256
#define IN_ 64
#define H_  768
#define G_  3072   // 4*H
#define K0_ 832    // IN_ + H_
#define K1_ 1536   // 2*H_
#define NWG0 96
#define NWGC 192   // compute WGs
#define NWGT 256   // + 2 aggregator WGs + 62 heater WGs
#define CB_  96
#define SLOT_ (CB_ * 64 * 8)   // ring slot elements = 49152

typedef __bf16 bf16_t;
typedef bf16_t bf16x8 __attribute__((ext_vector_type(8)));
typedef float  f32x4  __attribute__((ext_vector_type(4)));

__device__ __forceinline__ unsigned short f2bf(float f) {
    union { float f; unsigned u; } v; v.f = f;
    unsigned r = v.u + 0x7FFFu + ((v.u >> 16) & 1u);
    return (unsigned short)(r >> 16);
}
__device__ __forceinline__ float fast_sigm(float x) {
    float e = __builtin_amdgcn_exp2f(-1.44269504f * x);
    return __builtin_amdgcn_rcpf(1.0f + e);
}
__device__ __forceinline__ float fast_tanh(float x) {
    float e = __builtin_amdgcn_exp2f(2.88539008f * x);
    return (e - 1.0f) * __builtin_amdgcn_rcpf(e + 1.0f);
}
__device__ __forceinline__ void st_llc_u32(unsigned* p, unsigned v) {
    asm volatile("global_store_dword %0, %1, off sc1" :: "v"(p), "v"(v) : "memory");
}
#define MFMA16(a, b, c) __builtin_amdgcn_mfma_f32_16x16x32_bf16((a), (b), (c), 0, 0, 0)
#define AGENT_LD(p) __hip_atomic_load((p), __ATOMIC_RELAXED, __HIP_MEMORY_SCOPE_AGENT)

// wave-uniform wait on an epoch replica; lane0 loads, broadcast via sgpr.
__device__ __forceinline__ void wait_ep(int* rep, int s, int lane) {
    for (;;) {
        int e = 0;
        if (lane == 0) e = AGENT_LD(rep);
        e = __builtin_amdgcn_readfirstlane(e);
        if (e >= s) break;
        __builtin_amdgcn_s_sleep(1);
    }
    asm volatile("" ::: "memory");   // pin subsequent h loads after the wait
}

// ---------------- prep ----------------
__global__ __launch_bounds__(256) void prep_kernel(
    const float* __restrict__ x,
    const float* __restrict__ Wih0, const float* __restrict__ Whh0,
    const float* __restrict__ bih0, const float* __restrict__ bhh0,
    const float* __restrict__ Wih1, const float* __restrict__ Whh1,
    const float* __restrict__ bih1, const float* __restrict__ bhh1,
    unsigned short* __restrict__ xsT,    // [T][B][64]
    unsigned short* __restrict__ W0cat,  // [3072][832]
    unsigned short* __restrict__ W1cat,  // [3072][1536]
    float* __restrict__ bias0, float* __restrict__ bias1,
    int* __restrict__ ctrs)              // [4096]
{
    int i = blockIdx.x * blockDim.x + threadIdx.x;
    int stride = gridDim.x * blockDim.x;
    for (int j = i; j < B_ * T_ * IN_; j += stride) {
        int b = j >> 14;
        int t = (j >> 6) & (T_ - 1);
        int k = j & (IN_ - 1);
        xsT[(((size_t)t * B_) + b) * IN_ + k] = f2bf(x[j] * (1.0f / 1.5f));
    }
    for (int j = i; j < G_ * IN_; j += stride) {
        int r = j >> 6; int k = j & 63;
        W0cat[(size_t)r * K0_ + k] = f2bf(Wih0[j]);
    }
    for (int j = i; j < G_ * H_; j += stride) {
        int r = j / H_; int k = j - r * H_;
        W0cat[(size_t)r * K0_ + IN_ + k] = f2bf(Whh0[j]);
        W1cat[(size_t)r * K1_ + k]       = f2bf(Wih1[j]);
        W1cat[(size_t)r * K1_ + H_ + k]  = f2bf(Whh1[j]);
    }
    for (int j = i; j < G_; j += stride) {
        bias0[j] = bih0[j] + bhh0[j];
        bias1[j] = bih1[j] + bhh1[j];
    }
    for (int j = i; j < 4096; j += stride) ctrs[j] = 0;
}

// ---------------- persistent wavefront recurrence ----------------
__global__ __launch_bounds__(256) void lstm_persistent(
    const unsigned short* __restrict__ xsT,
    const unsigned short* __restrict__ W0cat,
    const unsigned short* __restrict__ W1cat,
    const float* __restrict__ bias0, const float* __restrict__ bias1,
    unsigned short* __restrict__ h1ring,  // [T][96][64][8]
    unsigned short* __restrict__ h2ring,  // [T][96][64][8]
    float* __restrict__ hf32,             // [B][H] fp32 (t = T-1)
    int* __restrict__ ctrs)
{
    __shared__ unsigned short ldsb[4][16][8];   // per-wave 16x8 output patch

    const int tid  = threadIdx.x;
    const int lane = tid & 63;
    const int wave = tid >> 6;
    const int wg   = blockIdx.x;

    int* done = &ctrs[2048];

    // ---------- aggregator WGs: one wave per (layer, m-tile) stream ---------
    if (wg == NWGC || wg == NWGC + 1) {
        const int layer = wg - NWGC;
        int* fl = &ctrs[layer * 512 + wave * 128];
        int* ep = &ctrs[1024 + layer * 512 + wave * 128];
        const int i1 = lane;              // flags 0..63
        const int i2 = 64 + (lane & 31);  // flags 64..95
        for (int e = 1; e <= T_; ++e) {
            for (;;) {
                int fa = AGENT_LD(&fl[i1]);
                int fb = AGENT_LD(&fl[i2]);
                if (__all(fa >= e && fb >= e)) break;
                __builtin_amdgcn_s_sleep(1);
            }
            if (lane < 8) st_llc_u32((unsigned*)&ep[lane * 16], (unsigned)e);
        }
        if (layer == 1 && wave == 3 && lane == 0)
            st_llc_u32((unsigned*)done, 1u);
        return;
    }
    // ---------- heater WGs: 8-way-ILP FMA streams, ~100% issue density ------
    if (wg > NWGC + 1) {
        float a0 = 1.0f, a1 = 1.1f, a2 = 1.2f, a3 = 1.3f;
        float a4 = 1.4f, a5 = 1.5f, a6 = 1.6f, a7 = 1.7f;
        const float bm = 1.0000001f, cm = 1e-9f;
        for (;;) {
            #pragma unroll
            for (int i = 0; i < 256; i++) {
                a0 = __builtin_fmaf(a0, bm, cm); a1 = __builtin_fmaf(a1, bm, cm);
                a2 = __builtin_fmaf(a2, bm, cm); a3 = __builtin_fmaf(a3, bm, cm);
                a4 = __builtin_fmaf(a4, bm, cm); a5 = __builtin_fmaf(a5, bm, cm);
                a6 = __builtin_fmaf(a6, bm, cm); a7 = __builtin_fmaf(a7, bm, cm);
            }
            asm volatile("" : "+v"(a0), "+v"(a1), "+v"(a2), "+v"(a3),
                              "+v"(a4), "+v"(a5), "+v"(a6), "+v"(a7));
            int d = 0;
            if (lane == 0) d = AGENT_LD(done);
            d = __builtin_amdgcn_readfirstlane(d);
            if (d != 0) break;
        }
        return;
    }

    const bool isL1 = (wg >= NWG0);
    const int cb   = isL1 ? (wg - NWG0) : wg;
    const int c0   = cb * 8;
    const int frow = lane & 15;
    const int q    = lane >> 4;
    const int kof  = q * 8;
    const int m0   = wave * 16;

    // per-wave sync pointers
    int* myflag = &ctrs[(isL1 ? 512 : 0) + wave * 128 + cb];
    int* rep0   = &ctrs[1024 + wave * 128 + (wg & 7) * 16];
    int* rep1   = &ctrs[1536 + wave * 128 + (wg & 7) * 16];

    const unsigned short* Wc = isL1 ? W1cat : W0cat;
    const int Kc = isL1 ? K1_ : K0_;
    int q0 = frow >> 3, col0 = c0 + (frow & 7);
    const unsigned short* Bp0 = Wc + (size_t)(q0 * H_ + col0) * Kc + kof;       // gates i,f
    const unsigned short* Bp1 = Wc + (size_t)((2 + q0) * H_ + col0) * Kc + kof; // gates g,o

    const float* bias = isL1 ? bias1 : bias0;
    const bool lowhalf = (lane & 15) < 8;
    const int ecol = c0 + (lane & 7);
    float bi = 0.f, bff = 0.f, bg = 0.f, bo = 0.f;
    if (lowhalf) {
        bi  = bias[0 * H_ + ecol];
        bff = bias[1 * H_ + ecol];
        bg  = bias[2 * H_ + ecol];
        bo  = bias[3 * H_ + ecol];
    }
    float creg[4] = {0.f, 0.f, 0.f, 0.f};

    const size_t aoff = (size_t)q * 512 + (size_t)(m0 + frow) * 8;
    const size_t stoff_e = (size_t)cb * 512 + (size_t)(m0 + (lane >> 2)) * 8
                         + (size_t)(lane & 3) * 2;

    if (!isL1) {
        // ------------- layer 0: superstep s computes t = s ------------------
        for (int s = 0; s < T_; ++s) {
            f32x4 acc0 = {0.f, 0.f, 0.f, 0.f};
            f32x4 acc1 = {0.f, 0.f, 0.f, 0.f};
            {   // xs contribution: independent of sync/h.
                const unsigned short* xsp =
                    xsT + ((size_t)s * B_ + m0 + frow) * IN_ + kof;
                #pragma unroll
                for (int ki = 0; ki < 2; ki++) {
                    bf16x8 a  = *(const bf16x8*)(xsp + ki * 32);
                    bf16x8 b0 = *(const bf16x8*)(Bp0 + ki * 32);
                    bf16x8 b1 = *(const bf16x8*)(Bp1 + ki * 32);
                    acc0 = MFMA16(a, b0, acc0);
                    acc1 = MFMA16(a, b1, acc1);
                }
            }
            if (s > 0) {
                wait_ep(rep0, s, lane);   // h1[s-1] rows of this m-tile ready
                const unsigned short* hr = h1ring + (size_t)(s - 1) * SLOT_ + aoff;
                #pragma unroll
                for (int kj = 0; kj < 24; kj++) {
                    bf16x8 a  = *(const bf16x8*)(hr + kj * 2048);
                    bf16x8 b0 = *(const bf16x8*)(Bp0 + (kj + 2) * 32);
                    bf16x8 b1 = *(const bf16x8*)(Bp1 + (kj + 2) * 32);
                    acc0 = MFMA16(a, b0, acc0);
                    acc1 = MFMA16(a, b1, acc1);
                }
            }
            f32x4 pacc0, pacc1;
            #pragma unroll
            for (int j = 0; j < 4; j++) {
                pacc0[j] = __shfl_xor(acc0[j], 8);
                pacc1[j] = __shfl_xor(acc1[j], 8);
            }
            if (lowhalf) {
                #pragma unroll
                for (int j = 0; j < 4; j++) {
                    float pi = acc0[j]  + bi;
                    float pf = pacc0[j] + bff;
                    float pg = acc1[j]  + bg;
                    float po = pacc1[j] + bo;
                    float cn = fast_sigm(pf) * creg[j] + fast_sigm(pi) * fast_tanh(pg);
                    float hn = fast_sigm(po) * fast_tanh(cn);
                    creg[j] = cn;
                    ldsb[wave][q * 4 + j][lane & 7] = f2bf(hn);
                }
            }
            // per-wave publish: wave-internal DS order; no barrier anywhere.
            unsigned v = ((const unsigned*)&ldsb[wave][0][0])[lane];
            st_llc_u32((unsigned*)(h1ring + (size_t)s * SLOT_ + stoff_e), v);
            asm volatile("s_waitcnt vmcnt(0)" ::: "memory");   // own 256B at MALL
            if (lane == 0) st_llc_u32((unsigned*)myflag, (unsigned)(s + 1));
        }
    } else {
        // ------------- layer 1: superstep s computes t = s - 1 --------------
        for (int s = 1; s <= T_; ++s) {
            const int t = s - 1;
            wait_ep(rep0, s, lane);               // h1[t] m-tile ready
            if (t > 0) wait_ep(rep1, t, lane);    // h2[t-1] m-tile ready
            f32x4 acc0 = {0.f, 0.f, 0.f, 0.f};
            f32x4 acc1 = {0.f, 0.f, 0.f, 0.f};
            const unsigned short* h1r = h1ring + (size_t)t * SLOT_ + aoff;
            #pragma unroll
            for (int ki = 0; ki < 24; ki++) {
                bf16x8 a  = *(const bf16x8*)(h1r + ki * 2048);
                bf16x8 b0 = *(const bf16x8*)(Bp0 + ki * 32);
                bf16x8 b1 = *(const bf16x8*)(Bp1 + ki * 32);
                acc0 = MFMA16(a, b0, acc0);
                acc1 = MFMA16(a, b1, acc1);
            }
            if (t > 0) {
                const unsigned short* h2r = h2ring + (size_t)(t - 1) * SLOT_ + aoff;
                #pragma unroll
                for (int ki = 0; ki < 24; ki++) {
                    bf16x8 a  = *(const bf16x8*)(h2r + ki * 2048);
                    bf16x8 b0 = *(const bf16x8*)(Bp0 + (ki + 24) * 32);
                    bf16x8 b1 = *(const bf16x8*)(Bp1 + (ki + 24) * 32);
                    acc0 = MFMA16(a, b0, acc0);
                    acc1 = MFMA16(a, b1, acc1);
                }
            }
            f32x4 pacc0, pacc1;
            #pragma unroll
            for (int j = 0; j < 4; j++) {
                pacc0[j] = __shfl_xor(acc0[j], 8);
                pacc1[j] = __shfl_xor(acc1[j], 8);
            }
            if (lowhalf) {
                #pragma unroll
                for (int j = 0; j < 4; j++) {
                    int row = m0 + q * 4 + j;
                    float pi = acc0[j]  + bi;
                    float pf = pacc0[j] + bff;
                    float pg = acc1[j]  + bg;
                    float po = pacc1[j] + bo;
                    float cn = fast_sigm(pf) * creg[j] + fast_sigm(pi) * fast_tanh(pg);
                    float hn = fast_sigm(po) * fast_tanh(cn);
                    creg[j] = cn;
                    ldsb[wave][q * 4 + j][lane & 7] = f2bf(hn);
                    if (t == T_ - 1) hf32[(size_t)row * H_ + ecol] = hn;
                }
            }
            unsigned v = ((const unsigned*)&ldsb[wave][0][0])[lane];
            st_llc_u32((unsigned*)(h2ring + (size_t)t * SLOT_ + stoff_e), v);
            asm volatile("s_waitcnt vmcnt(0)" ::: "memory");
            if (lane == 0) st_llc_u32((unsigned*)myflag, (unsigned)s);
        }
    }
}

// ---------------- head ----------------
__global__ __launch_bounds__(256) void head_kernel(
    const float* __restrict__ hlast,
    const float* __restrict__ W1, const float* __restrict__ b1,
    const float* __restrict__ W2, const float* __restrict__ b2,
    float* __restrict__ out)
{
    __shared__ float hs[H_];
    __shared__ float partial[4];
    int b = blockIdx.x;
    int tid = threadIdx.x;
    for (int j = tid; j < H_; j += 256) hs[j] = hlast[(size_t)b * H_ + j];
    __syncthreads();
    float z = 0.f;
    const float* w = W1 + (size_t)tid * H_;
    for (int j = 0; j < H_; j++) z += hs[j] * w[j];
    z += b1[tid];
    z = z / (1.0f + fabsf(z));
    float p = z * W2[tid];
    #pragma unroll
    for (int off = 32; off > 0; off >>= 1) p += __shfl_down(p, off, 64);
    if ((tid & 63) == 0) partial[tid >> 6] = p;
    __syncthreads();
    if (tid == 0) {
        float s = partial[0] + partial[1] + partial[2] + partial[3];
        out[b] = (s + b2[0]) * 70.0f;
    }
}

extern "C" void kernel_launch(void* const* d_in, const int* in_sizes, int n_in,
                              void* d_out, int out_size, void* d_ws, size_t ws_size,
                              hipStream_t stream) {
    const float* x    = (const float*)d_in[0];
    const float* Wih0 = (const float*)d_in[1];
    const float* Whh0 = (const float*)d_in[2];
    const float* bih0 = (const float*)d_in[3];
    const float* bhh0 = (const float*)d_in[4];
    const float* Wih1 = (const float*)d_in[5];
    const float* Whh1 = (const float*)d_in[6];
    const float* bih1 = (const float*)d_in[7];
    const float* bhh1 = (const float*)d_in[8];
    const float* W1   = (const float*)d_in[9];
    const float* b1   = (const float*)d_in[10];
    const float* W2   = (const float*)d_in[11];
    const float* b2   = (const float*)d_in[12];
    float* out = (float*)d_out;

    char* w = (char*)d_ws;
    int* ctrs = (int*)w;                          w += 16384;
    unsigned short* h1ring = (unsigned short*)w;  w += (size_t)T_ * SLOT_ * 2;
    unsigned short* h2ring = (unsigned short*)w;  w += (size_t)T_ * SLOT_ * 2;
    unsigned short* xsT    = (unsigned short*)w;  w += (size_t)B_ * T_ * IN_ * 2;
    unsigned short* W0cat  = (unsigned short*)w;  w += (size_t)G_ * K0_ * 2;
    unsigned short* W1cat  = (unsigned short*)w;  w += (size_t)G_ * K1_ * 2;
    float* bias0 = (float*)w;                     w += G_ * 4;
    float* bias1 = (float*)w;                     w += G_ * 4;
    float* hf32  = (float*)w;                     w += (size_t)B_ * H_ * 4;

    prep_kernel<<<1024, 256, 0, stream>>>(x, Wih0, Whh0, bih0, bhh0,
                                          Wih1, Whh1, bih1, bhh1,
                                          xsT, W0cat, W1cat, bias0, bias1, ctrs);
    lstm_persistent<<<NWGT, 256, 0, stream>>>(xsT, W0cat, W1cat, bias0, bias1,
                                              h1ring, h2ring, hf32, ctrs);
    head_kernel<<<B_, 256, 0, stream>>>(hf32, W1, b1, W2, b2, out);
}